// Round 8
// baseline (441.462 us; speedup 1.0000x reference)
//
#include <hip/hip_runtime.h>
#include <stdint.h>

// SpatialHyperedgeMP: out = ((inc + head) @ cur) / rowsum(inc + head)
//   head_ij = (inc_ij > 0) / sqrt(cnt_i),  cnt_i = #positives in row i
// Decomposition (single fused pass over inc):
//   out[i] = (inc@cur + invs_i * (mask@cur)) * rdeg_i
//   invs_i = 1/sqrt(cnt_i),  rdeg_i = 1/(s1_i + sqrt(cnt_i))
//   s1 (fp64) and cnt (int) accumulated during A staging -> exact denominator.
//
// R8: occupancy fix. R7 post-mortem: all pipes idle, 2 waves/SIMD can't cover
// the per-tile barrier chain. Now BM=16, 4-wave blocks, 1024 blocks = 4/CU =
// 4 waves/SIMD; independent blocks hide each other's stalls (no shared barrier).
// DS stays lean (A-frag dup only 4x, rg=1: 4 b128 reads/wave/tile).
// Swizzle: nt = id&1 -> each XCD streams one 4MB B-chunk (L2-resident);
// the 4 blocks/CU take 4 consecutive mt -> one 64-row A panel per CU.
//
// ws usage: 8MB B chunks only.

#define NROWS 8192
#define DDIM  512

typedef float f32x4 __attribute__((ext_vector_type(4)));
typedef short s16x8 __attribute__((ext_vector_type(8)));

__device__ __forceinline__ unsigned short f2bf(float f) {
  union { float f; unsigned int u; } c; c.f = f;
  unsigned int u = c.u;
  unsigned int r = u + 0x7FFFu + ((u >> 16) & 1u);
  return (unsigned short)(r >> 16);
}

// ---------------- kernel 1: B prep (cur -> bf16 chunked-transposed) ----------------
// chunk layout: nt(2) x kt(128): 32KB chunk = [kg=8][nn=256][e=8] bf16
__global__ __launch_bounds__(256) void bprep_kernel(const float* __restrict__ cur,
                                                    unsigned char* __restrict__ bws) {
  int idx = blockIdx.x * 256 + threadIdx.x;  // 0..524287
  int n = idx & 511;
  int kg9 = idx >> 9;  // 0..1023
  int kt = kg9 >> 3;
  int kg = kg9 & 7;
  int k0 = kt * 64 + kg * 8;
  union { unsigned short h[8]; uint4 q; } u;
#pragma unroll
  for (int e = 0; e < 8; ++e)
    u.h[e] = f2bf(cur[(size_t)(k0 + e) * DDIM + n]);
  int nt = n >> 8, nn = n & 255;
  size_t off = ((size_t)(nt * 128 + kt) << 15) + ((size_t)kg << 12) + ((size_t)nn << 4);
  *(uint4*)(bws + off) = u.q;
}

// ---------------- kernel 2: fused stats + dual-GEMM ----------------
// BM=16 BN=256 BK=64, 256 threads = 4 waves (1M x 4N), wave tile 16x64.
// LDS (8.3KB): A0,A1,M0,M1 = 2KB each ([kg=8][slot=16][e=8] bf16, slot=(row^kg)&15).
// B frags: registers, 1 tile ahead from ws. A regs: 2 tiles ahead.
// Only manual wait: lgkmcnt(0) before the per-tile barrier (A/M ds_writes).

#define FENCE() __builtin_amdgcn_sched_barrier(0)
#define BARRIER() __builtin_amdgcn_s_barrier()
#define WAITLGKM() asm volatile("s_waitcnt lgkmcnt(0)" ::: "memory")

__global__ __launch_bounds__(256, 4) void gemm_kernel(const float* __restrict__ inc,
                                                      const unsigned char* __restrict__ bws,
                                                      float* __restrict__ out) {
  __shared__ __align__(16) unsigned char smem[8192];
  unsigned char* const aBuf0 = smem;
  unsigned char* const aBuf1 = smem + 2048;
  unsigned char* const mBuf0 = smem + 4096;
  unsigned char* const mBuf1 = smem + 6144;

  const int tid = threadIdx.x;
  const int lane = tid & 63;
  const int wv = tid >> 6;        // 0..3
  // Swizzle (assume XCD = id%8, XCD round-robins its blocks over its 32 CUs):
  //   nt = id&1            -> XCD parity fixes the B chunk (4MB, L2-resident)
  //   the 4 blocks a CU receives (j=0..3) get consecutive mt -> 64-row A panel/CU;
  //   nt-partners are ids 2q,2q+1 -> dispatched together -> L3 dedups A.
  const int id = blockIdx.x;      // 0..1023
  const int nt = id & 1;
  const int mt = ((id >> 1) & 3) * 128 + ((id >> 3) & 31) * 4 + (id >> 8);  // bijective 0..511
  const int brow = mt * 16;
  const int bcol = nt * 256;

  // A ownership: thread -> (row sm 0..15, float4-slot sp 0..15); per tile:
  // 1 float4 load, one b64 A-write + one b64 M-write.
  const int sm = tid >> 4;
  const int sp = tid & 15;
  const int kgw = sp >> 1, half = sp & 1;
  const float4* gAr = (const float4*)(inc + (size_t)(brow + sm) * NROWS) + sp;
  const int aWr = (kgw << 8) + (((sm ^ kgw) & 15) << 4) + (half << 3);

  const unsigned char* gBb = bws + ((size_t)(nt * 128) << 15);

  // fragment offsets
  int aOff[2];      // LDS byte offsets for A/M frags (rg=1)
  int bOff[8];      // ws byte offsets (within a 32KB kt-chunk) for B frags
#pragma unroll
  for (int kh = 0; kh < 2; ++kh) {
    int kg = kh * 4 + (lane >> 4);
    int r = lane & 15;
    aOff[kh] = (kg << 8) + (((r ^ kg) & 15) << 4);
#pragma unroll
    for (int cg = 0; cg < 4; ++cg)
      bOff[kh * 4 + cg] = (kg << 12) + ((wv * 64 + cg * 16 + (lane & 15)) << 4);
  }

  f32x4 acc1[4], acc2[4];
#pragma unroll
  for (int b = 0; b < 4; ++b) {
    acc1[b] = (f32x4){0.f, 0.f, 0.f, 0.f};
    acc2[b] = (f32x4){0.f, 0.f, 0.f, 0.f};
  }

  double s1d = 0.0;
  int cnt = 0;
  float4 x, y;
  s16x8 bA[8], bB[8];   // B frag double reg-buffer (static indices after unroll)

#define ISSUE_A(d, KT) do { d = gAr[(KT) * 16]; } while (0)

#define LOADB(BS, KT) do {                                                                \
    const unsigned char* _g = gBb + ((size_t)(KT) << 15);                                 \
    _Pragma("unroll")                                                                     \
    for (int _i = 0; _i < 8; ++_i) BS[_i] = *(const s16x8*)(_g + bOff[_i]);               \
  } while (0)

// stage A tile: exact stats, RNE bf16 via v_cvt_pk, mask bf16 (1.0/0.0) -> LDS.
#define XFORM(s0, ADST, MDST) do {                                                        \
    s1d += (double)s0.x + (double)s0.y + (double)s0.z + (double)s0.w;                     \
    cnt += (s0.x > 0.f) + (s0.y > 0.f) + (s0.z > 0.f) + (s0.w > 0.f);                     \
    unsigned dlo, dhi;                                                                    \
    asm("v_cvt_pk_bf16_f32 %0, %1, %2" : "=v"(dlo) : "v"(s0.x), "v"(s0.y));               \
    asm("v_cvt_pk_bf16_f32 %0, %1, %2" : "=v"(dhi) : "v"(s0.z), "v"(s0.w));               \
    unsigned mlo = (s0.x > 0.f ? 0x3F80u : 0u) | (s0.y > 0.f ? 0x3F800000u : 0u);         \
    unsigned mhi = (s0.z > 0.f ? 0x3F80u : 0u) | (s0.w > 0.f ? 0x3F800000u : 0u);         \
    *(unsigned long long*)((ADST) + aWr) =                                                \
        (unsigned long long)dlo | ((unsigned long long)dhi << 32);                        \
    *(unsigned long long*)((MDST) + aWr) =                                                \
        (unsigned long long)mlo | ((unsigned long long)mhi << 32);                        \
  } while (0)

#define MFMA_TILE(AC, MC, BS) do {                                                        \
    __builtin_amdgcn_s_setprio(1);                                                        \
    _Pragma("unroll")                                                                     \
    for (int kh = 0; kh < 2; ++kh) {                                                      \
      s16x8 af = *(const s16x8*)((AC) + aOff[kh]);                                        \
      s16x8 am = *(const s16x8*)((MC) + aOff[kh]);                                        \
      _Pragma("unroll")                                                                   \
      for (int cg = 0; cg < 4; ++cg) {                                                    \
        acc1[cg] = __builtin_amdgcn_mfma_f32_16x16x32_bf16(af, BS[kh * 4 + cg],           \
                                                           acc1[cg], 0, 0, 0);           \
        acc2[cg] = __builtin_amdgcn_mfma_f32_16x16x32_bf16(am, BS[kh * 4 + cg],           \
                                                           acc2[cg], 0, 0, 0);           \
      }                                                                                   \
    }                                                                                     \
    __builtin_amdgcn_s_setprio(0);                                                        \
  } while (0)

#define SYNC() do { FENCE(); WAITLGKM(); FENCE(); BARRIER(); FENCE(); } while (0)

  // ---- prologue ----
  ISSUE_A(x, 0);
  LOADB(bA, 0);
  ISSUE_A(y, 1);
  XFORM(x, aBuf0, mBuf0);        // compiler auto-waits A(0) regs precisely
  SYNC();

  // ---- steady: tiles 0..125, unrolled by 2 for static reg/buffer names ----
  for (int kt = 0; kt < 126; kt += 2) {
    // even tile kt: uses aBuf0/mBuf0 + bA
    ISSUE_A(x, kt + 2);
    LOADB(bB, kt + 1);
    FENCE();                     // pin load issue before the MFMA cluster
    MFMA_TILE(aBuf0, mBuf0, bA);
    XFORM(y, aBuf1, mBuf1);
    SYNC();
    // odd tile kt+1: uses aBuf1/mBuf1 + bB
    ISSUE_A(y, kt + 3);
    LOADB(bA, kt + 2);
    FENCE();
    MFMA_TILE(aBuf1, mBuf1, bB);
    XFORM(x, aBuf0, mBuf0);
    SYNC();
  }

  // ---- tail: tile 126 ----
  LOADB(bB, 127);
  FENCE();
  MFMA_TILE(aBuf0, mBuf0, bA);
  XFORM(y, aBuf1, mBuf1);        // A(127)
  SYNC();
  // ---- tail: tile 127 ----
  MFMA_TILE(aBuf1, mBuf1, bB);

  // ---- stats reduction: 16 lanes per row (consecutive lanes in wave) ----
#pragma unroll
  for (int o = 1; o < 16; o <<= 1) {
    s1d += __shfl_xor(s1d, o);
    cnt += __shfl_xor(cnt, o);
  }
  __syncthreads();               // K-loop fully done -> safe to reuse aBuf0
  float* const invsS = (float*)aBuf0;   // 16 floats
  float* const rdegS = invsS + 16;      // 16 floats
  if (sp == 0) {
    double sq = sqrt((double)cnt);
    invsS[sm] = (cnt > 0) ? (float)(1.0 / sq) : 0.0f;
    rdegS[sm] = (float)(1.0 / (s1d + sq));
  }
  __syncthreads();

  // ---- epilogue: (acc1 + invs*acc2) * rdeg, store fp32 ----
  {
    int rb = (lane >> 4) << 2;
#pragma unroll
    for (int cg = 0; cg < 4; ++cg) {
      int col = bcol + wv * 64 + cg * 16 + (lane & 15);
#pragma unroll
      for (int r = 0; r < 4; ++r) {
        int rl = rb + r;
        out[(size_t)(brow + rl) * DDIM + col] =
            (acc1[cg][r] + invsS[rl] * acc2[cg][r]) * rdegS[rl];
      }
    }
  }
#undef ISSUE_A
#undef LOADB
#undef XFORM
#undef MFMA_TILE
#undef SYNC
}

extern "C" void kernel_launch(void* const* d_in, const int* in_sizes, int n_in,
                              void* d_out, int out_size, void* d_ws, size_t ws_size,
                              hipStream_t stream) {
  const float* cur = (const float*)d_in[0];          // [8192, 512] fp32
  const float* incm = (const float*)d_in[1];         // [8192, 8192] fp32
  float* out = (float*)d_out;                        // [8192, 512] fp32
  unsigned char* bws = (unsigned char*)d_ws;         // 8MB B chunks

  hipLaunchKernelGGL(bprep_kernel, dim3((NROWS * DDIM / 8) / 256), dim3(256), 0, stream,
                     cur, bws);
  hipLaunchKernelGGL(gemm_kernel, dim3(1024), dim3(256), 0, stream, incm, bws, out);
}